// Round 12
// baseline (112.590 us; speedup 1.0000x reference)
//
#include <hip/hip_runtime.h>

// DCNv2, fp32 in/out, all matmul-shaped work on bf16 MFMA.
// Round 12: DIAGNOSTIC SPLIT of the R9-best fused kernel (43us) at the A/B
// boundary -> two dispatches with separate rocprof rows. Arithmetic is
// byte-for-byte R9 (bit-identical output); offsets go through global offs
// (4.7MB, L2-resident, same XCD swizzle for kA/kB -> L2 hits).
//  - pre_kernel: x NCHW -> xT_hi/xT_lo bf16 NHWC (split-bf16) + weight A-frags
//  - offA_kernel (kA): offset conv im2col GEMM (3-term split-bf16), dbuf
//    1 barrier/kk, wave=(ct,pg-pair) -> offs f32 global.
//  - defB_kernel (kB): bilinear sample (cvt_pk pack) -> LDS dbuf B-frags ->
//    deform GEMM, wave=cout-tile (A-frag dedup), 16KB LDS only.
// ws: xThi 8388608 | xTlo 8388608 | offs 4718592 | wdA 73728 | woAhi 36864 | woAlo 36864

#define BATCH 4
#define CIN   64
#define COUT  64
#define HH    128
#define WW    128
#define HWPIX (HH*WW)

typedef __attribute__((ext_vector_type(8))) short short8;   // 8 bf16 (4 VGPRs)
typedef __attribute__((ext_vector_type(4))) float floatx4;  // MFMA C/D

__device__ __forceinline__ unsigned short f2bf(float f) {   // RNE f32->bf16
  unsigned int u = __float_as_uint(f);
  unsigned int r = u + 0x7fffu + ((u >> 16) & 1u);
  return (unsigned short)(r >> 16);
}
__device__ __forceinline__ float bf2f(unsigned short h) { return __uint_as_float(((unsigned int)h) << 16); }
__device__ __forceinline__ float lo16f(unsigned int u) { return __uint_as_float(u << 16); }
__device__ __forceinline__ float hi16f(unsigned int u) { return __uint_as_float(u & 0xffff0000u); }

// 2-channel bilinear blend; pack via HW RNE convert (== f2bf pair).
__device__ __forceinline__ unsigned int bilin2(unsigned int u00, unsigned int u01,
                                               unsigned int u10, unsigned int u11,
                                               float w00, float w01, float w10, float w11) {
  float lo = w00 * lo16f(u00) + w01 * lo16f(u01) + w10 * lo16f(u10) + w11 * lo16f(u11);
  float hi = w00 * hi16f(u00) + w01 * hi16f(u01) + w10 * hi16f(u10) + w11 * hi16f(u11);
  unsigned int r;
  asm("v_cvt_pk_bf16_f32 %0, %1, %2" : "=v"(r) : "v"(lo), "v"(hi));
  return r;
}

// LDS byte-offset swizzle: fold bits 9-10 into bits 4-5 (involution, <8KB).
__device__ __forceinline__ int swz(int a) { return a ^ (((a >> 9) & 3) << 4); }

// Fused preprocessing (unchanged):
__global__ __launch_bounds__(256) void pre_kernel(const float* __restrict__ x,
                                                  const float* __restrict__ wo,
                                                  const float* __restrict__ wd,
                                                  unsigned short* __restrict__ xThi,
                                                  unsigned short* __restrict__ xTlo,
                                                  unsigned short* __restrict__ wdA,
                                                  unsigned short* __restrict__ woAhi,
                                                  unsigned short* __restrict__ woAlo) {
  int tid = threadIdx.x;
  if (blockIdx.x < 4096) {
    __shared__ float tile[32][33];   // [c_local][p_local]
    int t = blockIdx.x;
    int b = t >> 10, rem = t & 1023;
    int c0 = (rem >> 9) * 32, p0 = (rem & 511) * 32;
    int tx = tid & 31, ty = tid >> 5;      // (32,8)
    const float* xb = x + (size_t)b * CIN * HWPIX;
    size_t boff = (size_t)b * HWPIX * CIN;
#pragma unroll
    for (int i = 0; i < 4; i++)
      tile[ty + i * 8][tx] = xb[(size_t)(c0 + ty + i * 8) * HWPIX + p0 + tx];
    __syncthreads();
#pragma unroll
    for (int i = 0; i < 2; i++) {
      int tt = tid + i * 256;       // 0..511 = 32 rows * 16 cin-pairs
      int row = tt >> 4;
      int cp = tt & 15;
      float v0 = tile[cp * 2][row], v1 = tile[cp * 2 + 1][row];
      unsigned short h0 = f2bf(v0), h1 = f2bf(v1);
      unsigned short l0 = f2bf(v0 - bf2f(h0)), l1 = f2bf(v1 - bf2f(h1));
      size_t o = boff + (size_t)(p0 + row) * CIN + c0 + cp * 2;
      *(ushort2*)&xThi[o] = make_ushort2(h0, h1);
      *(ushort2*)&xTlo[o] = make_ushort2(l0, l1);
    }
  } else {
    int t = (blockIdx.x - 4096) * 256 + tid;
    if (t < 36864) {
      int j = t & 7, lane = (t >> 3) & 63, ct = (t >> 9) & 3, kc = (t >> 11) & 1, kk = t >> 12;
      int cout = ct * 16 + (lane & 15);
      int cin  = kc * 32 + (lane >> 4) * 8 + j;
      wdA[t] = f2bf(wd[(size_t)(cout * CIN + cin) * 9 + kk]);
    }
    int t2 = t - 36864;
    if (t2 >= 0 && t2 < 18432) {
      int j = t2 & 7, lane = (t2 >> 3) & 63, ct = (t2 >> 9) & 1, kc = (t2 >> 10) & 1, kk = t2 >> 11;
      int cout = ct * 16 + (lane & 15);          // conv channel 0..31 (valid < 18)
      int cin  = kc * 32 + (lane >> 4) * 8 + j;
      float v = (cout < 18) ? wo[(size_t)(cout * CIN + cin) * 9 + kk] : 0.f;
      unsigned short h = f2bf(v);
      woAhi[t2] = h;
      woAlo[t2] = f2bf(v - bf2f(h));
    }
  }
}

// kA: offset conv (R9 phase A verbatim), writes offs f32.
// Block: 64 px tile, 256 thr = 4 waves; wave w -> (ctA=w&1, pgA=(w>>1)*2).
__global__ __launch_bounds__(256) void offA_kernel(const unsigned short* __restrict__ xThi,
                                                   const unsigned short* __restrict__ xTlo,
                                                   const unsigned short* __restrict__ woAhi,
                                                   const unsigned short* __restrict__ woAlo,
                                                   float* __restrict__ offs) {
  __shared__ unsigned short sBhi2[2][4096];
  __shared__ unsigned short sBlo2[2][4096];
  char* sHc = (char*)sBhi2;
  char* sLc = (char*)sBlo2;

  int tid = threadIdx.x;
  int hw = blockIdx.x;
  int bid = (hw & 7) * 128 + (hw >> 3);    // XCD-contiguous y bands
  int b = bid >> 8, r = bid & 255, y = r >> 1, x0 = (r & 1) << 6;

  int p1 = tid >> 2, si = tid & 3;
  int lane = tid & 63, w = tid >> 6;

  const unsigned short* xhib = xThi + (size_t)b * HWPIX * CIN;
  const unsigned short* xlob = xTlo + (size_t)b * HWPIX * CIN;

  int wq = p1 >> 4, iq = p1 & 15;
  int kcd = si >> 1, qb = si & 1;
  int wb0 = ((((wq * 2 + kcd) * 64) + qb * 32 + iq) * 8) * 2;
  int wb1 = wb0 + 256;
  int swb0 = swz(wb0), swb1 = swz(wb1);
  int brb0[4], brb1[4];
#pragma unroll
  for (int pg = 0; pg < 4; pg++) {
    brb0[pg] = swz(pg * 2048 + lane * 16);
    brb1[pg] = swz(pg * 2048 + 1024 + lane * 16);
  }

  int xp = x0 + p1;

  floatx4 oacc[2];
  oacc[0] = (floatx4){0.f, 0.f, 0.f, 0.f};
  oacc[1] = (floatx4){0.f, 0.f, 0.f, 0.f};
  int ctA = w & 1, pgA = (w >> 1) * 2;

  auto ldA = [&](int kk, uint4& h0, uint4& h1, uint4& l0, uint4& l1) {
    int ys = y - 1 + kk / 3;
    int xs = xp - 1 + kk % 3;
    bool valid = (ys >= 0) && (ys < HH) && (xs >= 0) && (xs < WW);
    h0 = (uint4){0, 0, 0, 0}; h1 = h0; l0 = h0; l1 = h0;
    if (valid) {
      const unsigned short* ph = xhib + (size_t)(ys * WW + xs) * CIN + si * 16;
      const unsigned short* pl = xlob + (size_t)(ys * WW + xs) * CIN + si * 16;
      h0 = *(const uint4*)ph; h1 = *(const uint4*)(ph + 8);
      l0 = *(const uint4*)pl; l1 = *(const uint4*)(pl + 8);
    }
  };
  auto stageA = [&](int nxt, const uint4& h0, const uint4& h1, const uint4& l0, const uint4& l1) {
    *(uint4*)(sHc + nxt * 8192 + swb0) = h0;
    *(uint4*)(sHc + nxt * 8192 + swb1) = h1;
    *(uint4*)(sLc + nxt * 8192 + swb0) = l0;
    *(uint4*)(sLc + nxt * 8192 + swb1) = l1;
  };
  auto mfmaA = [&](int kk, int cur) {
    const short8* Ah = (const short8*)(woAhi + (size_t)kk * 2048);
    const short8* Al = (const short8*)(woAlo + (size_t)kk * 2048);
    short8 ah0 = Ah[ctA * 64 + lane], ah1 = Ah[128 + ctA * 64 + lane];
    short8 al0 = Al[ctA * 64 + lane], al1 = Al[128 + ctA * 64 + lane];
#pragma unroll
    for (int pgi = 0; pgi < 2; pgi++) {
      int pg = pgA + pgi;
      short8 bh0 = *(const short8*)(sHc + cur * 8192 + brb0[pg]);
      short8 bh1 = *(const short8*)(sHc + cur * 8192 + brb1[pg]);
      short8 bl0 = *(const short8*)(sLc + cur * 8192 + brb0[pg]);
      short8 bl1 = *(const short8*)(sLc + cur * 8192 + brb1[pg]);
      oacc[pgi] = __builtin_amdgcn_mfma_f32_16x16x32_bf16(ah0, bh0, oacc[pgi], 0, 0, 0);
      oacc[pgi] = __builtin_amdgcn_mfma_f32_16x16x32_bf16(ah0, bl0, oacc[pgi], 0, 0, 0);
      oacc[pgi] = __builtin_amdgcn_mfma_f32_16x16x32_bf16(al0, bh0, oacc[pgi], 0, 0, 0);
      oacc[pgi] = __builtin_amdgcn_mfma_f32_16x16x32_bf16(ah1, bh1, oacc[pgi], 0, 0, 0);
      oacc[pgi] = __builtin_amdgcn_mfma_f32_16x16x32_bf16(ah1, bl1, oacc[pgi], 0, 0, 0);
      oacc[pgi] = __builtin_amdgcn_mfma_f32_16x16x32_bf16(al1, bh1, oacc[pgi], 0, 0, 0);
    }
  };

  {
    uint4 h0c, h1c, l0c, l1c;
    ldA(0, h0c, h1c, l0c, l1c);
    stageA(0, h0c, h1c, l0c, l1c);
    __syncthreads();
#pragma unroll 1
    for (int kk = 0; kk < 9; kk++) {
      uint4 h0n, h1n, l0n, l1n;
      if (kk < 8) ldA(kk + 1, h0n, h1n, l0n, l1n);
      mfmaA(kk, kk & 1);
      if (kk < 8) stageA((kk + 1) & 1, h0n, h1n, l0n, l1n);
      __syncthreads();
    }
  }

  // write offs: D col = lane&15 (px in pg tile), row = (lane>>4)*4 + rr
  {
    int rowb = (lane >> 4) * 4;
    float* ob = offs + (size_t)b * 18 * HWPIX + y * WW;
#pragma unroll
    for (int pgi = 0; pgi < 2; pgi++)
#pragma unroll
      for (int rr = 0; rr < 4; rr++) {
        int row = ctA * 16 + rowb + rr;
        if (row < 18) ob[(size_t)row * HWPIX + x0 + (pgA + pgi) * 16 + (lane & 15)] = oacc[pgi][rr];
      }
  }
}

// kB: bilinear sample + deform GEMM (R9 phase B verbatim), reads offs f32.
// Block: 64 px tile, 256 thr = 4 waves; wave w -> ct=w, pg-loop 0..3.
__global__ __launch_bounds__(256) void defB_kernel(const unsigned short* __restrict__ xThi,
                                                   const float* __restrict__ offs,
                                                   const unsigned short* __restrict__ wdA,
                                                   float* __restrict__ out) {
  __shared__ unsigned short sB2[2][4096];   // 16 KB dbuf only
  char* sHc = (char*)sB2;

  int tid = threadIdx.x;
  int hw = blockIdx.x;
  int bid = (hw & 7) * 128 + (hw >> 3);    // same XCD mapping as kA -> L2 hits
  int b = bid >> 8, r = bid & 255, y = r >> 1, x0 = (r & 1) << 6;

  int p1 = tid >> 2, si = tid & 3;
  int lane = tid & 63, w = tid >> 6;

  const unsigned short* xhib = xThi + (size_t)b * HWPIX * CIN;
  const float* ob = offs + (size_t)b * 18 * HWPIX + y * WW;

  int wq = p1 >> 4, iq = p1 & 15;
  int kcd = si >> 1, qb = si & 1;
  int wb0 = ((((wq * 2 + kcd) * 64) + qb * 32 + iq) * 8) * 2;
  int wb1 = wb0 + 256;
  int swb0 = swz(wb0), swb1 = swz(wb1);
  int brb0[4], brb1[4];
#pragma unroll
  for (int pg = 0; pg < 4; pg++) {
    brb0[pg] = swz(pg * 2048 + lane * 16);
    brb1[pg] = swz(pg * 2048 + 1024 + lane * 16);
  }
  int xp = x0 + p1;

  floatx4 acc[4];
#pragma unroll
  for (int pg = 0; pg < 4; pg++) acc[pg] = (floatx4){0.f, 0.f, 0.f, 0.f};

  struct BS {
    float w00, w01, w10, w11;
    uint4 a00, a01, a10, a11, b00, b01, b10, b11;
  };
  auto ldB = [&](int kk) -> BS {
    BS s;
    float dy = ob[(size_t)(2 * kk) * HWPIX + xp];
    float dx = ob[(size_t)(2 * kk + 1) * HWPIX + xp];
    float ys = (float)(y - 1 + kk / 3) + dy;
    float xs = (float)(xp - 1 + kk % 3) + dx;
    float y0f = floorf(ys), x0f = floorf(xs);
    float wy = ys - y0f, wx = xs - x0f;
    int iy0 = (int)y0f, ix0 = (int)x0f;
    int iy1 = iy0 + 1, ix1 = ix0 + 1;
    s.w00 = (1.f - wy) * (1.f - wx); s.w01 = (1.f - wy) * wx;
    s.w10 = wy * (1.f - wx);         s.w11 = wy * wx;
    bool vy0 = (iy0 >= 0) && (iy0 < HH), vy1 = (iy1 >= 0) && (iy1 < HH);
    bool vx0 = (ix0 >= 0) && (ix0 < WW), vx1 = (ix1 >= 0) && (ix1 < WW);
    if (!(vy0 && vx0)) s.w00 = 0.f;
    if (!(vy0 && vx1)) s.w01 = 0.f;
    if (!(vy1 && vx0)) s.w10 = 0.f;
    if (!(vy1 && vx1)) s.w11 = 0.f;
    int cy0 = min(max(iy0, 0), HH - 1), cy1 = min(max(iy1, 0), HH - 1);
    int cx0 = min(max(ix0, 0), WW - 1), cx1 = min(max(ix1, 0), WW - 1);
    const unsigned short* q00 = xhib + (size_t)(cy0 * WW + cx0) * CIN + si * 16;
    const unsigned short* q01 = xhib + (size_t)(cy0 * WW + cx1) * CIN + si * 16;
    const unsigned short* q10 = xhib + (size_t)(cy1 * WW + cx0) * CIN + si * 16;
    const unsigned short* q11 = xhib + (size_t)(cy1 * WW + cx1) * CIN + si * 16;
    s.a00 = *(const uint4*)q00; s.a01 = *(const uint4*)q01;
    s.a10 = *(const uint4*)q10; s.a11 = *(const uint4*)q11;
    s.b00 = *(const uint4*)(q00 + 8); s.b01 = *(const uint4*)(q01 + 8);
    s.b10 = *(const uint4*)(q10 + 8); s.b11 = *(const uint4*)(q11 + 8);
    return s;
  };
  auto blendStoreB = [&](int nxt, const BS& s) {
    uint4 o0, o1;
    o0.x = bilin2(s.a00.x, s.a01.x, s.a10.x, s.a11.x, s.w00, s.w01, s.w10, s.w11);
    o0.y = bilin2(s.a00.y, s.a01.y, s.a10.y, s.a11.y, s.w00, s.w01, s.w10, s.w11);
    o0.z = bilin2(s.a00.z, s.a01.z, s.a10.z, s.a11.z, s.w00, s.w01, s.w10, s.w11);
    o0.w = bilin2(s.a00.w, s.a01.w, s.a10.w, s.a11.w, s.w00, s.w01, s.w10, s.w11);
    o1.x = bilin2(s.b00.x, s.b01.x, s.b10.x, s.b11.x, s.w00, s.w01, s.w10, s.w11);
    o1.y = bilin2(s.b00.y, s.b01.y, s.b10.y, s.b11.y, s.w00, s.w01, s.w10, s.w11);
    o1.z = bilin2(s.b00.z, s.b01.z, s.b10.z, s.b11.z, s.w00, s.w01, s.w10, s.w11);
    o1.w = bilin2(s.b00.w, s.b01.w, s.b10.w, s.b11.w, s.w00, s.w01, s.w10, s.w11);
    *(uint4*)(sHc + nxt * 8192 + swb0) = o0;
    *(uint4*)(sHc + nxt * 8192 + swb1) = o1;
  };
  auto mfmaB = [&](int kk, int cur) {
    const short8* Ap = (const short8*)(wdA + (size_t)kk * 4096);
    short8 a0 = Ap[w * 64 + lane];          // this wave's ct only (A dedup)
    short8 a1 = Ap[256 + w * 64 + lane];
#pragma unroll
    for (int pg = 0; pg < 4; pg++) {
      short8 bv0 = *(const short8*)(sHc + cur * 8192 + brb0[pg]);
      short8 bv1 = *(const short8*)(sHc + cur * 8192 + brb1[pg]);
      acc[pg] = __builtin_amdgcn_mfma_f32_16x16x32_bf16(a0, bv0, acc[pg], 0, 0, 0);
      acc[pg] = __builtin_amdgcn_mfma_f32_16x16x32_bf16(a1, bv1, acc[pg], 0, 0, 0);
    }
  };

  {
    BS s0 = ldB(0);
    blendStoreB(0, s0);
    __syncthreads();
#pragma unroll 1
    for (int kk = 0; kk < 9; kk++) {
      BS sn;
      if (kk < 8) sn = ldB(kk + 1);
      mfmaB(kk, kk & 1);
      if (kk < 8) blendStoreB((kk + 1) & 1, sn);
      __syncthreads();
    }
  }

  int rowb = (lane >> 4) * 4;
  float* outb = out + (size_t)b * COUT * HWPIX + y * WW + x0 + (lane & 15);
#pragma unroll
  for (int pg = 0; pg < 4; pg++)
#pragma unroll
    for (int rr = 0; rr < 4; rr++)
      outb[(size_t)(w * 16 + rowb + rr) * HWPIX + pg * 16] = acc[pg][rr];
}

extern "C" void kernel_launch(void* const* d_in, const int* in_sizes, int n_in,
                              void* d_out, int out_size, void* d_ws, size_t ws_size,
                              hipStream_t stream) {
  const float* x  = (const float*)d_in[0];
  const float* wo = (const float*)d_in[1];
  const float* wd = (const float*)d_in[2];
  float* out = (float*)d_out;

  char* wsb = (char*)d_ws;
  unsigned short* xThi  = (unsigned short*)wsb;                         // 8,388,608 B
  unsigned short* xTlo  = (unsigned short*)(wsb + 8388608);             // 8,388,608 B
  float* offs           = (float*)(wsb + 16777216);                     // 4,718,592 B
  unsigned short* wdA   = (unsigned short*)(wsb + 16777216 + 4718592);  // 73,728 B
  unsigned short* woAhi = (unsigned short*)(wsb + 21495808 + 73728);    // 36,864 B
  unsigned short* woAlo = (unsigned short*)(wsb + 21569536 + 36864);    // 36,864 B

  pre_kernel<<<dim3(4096 + 216), dim3(256), 0, stream>>>(x, wo, wd, xThi, xTlo, wdA, woAhi, woAlo);
  offA_kernel<<<dim3(BATCH * HWPIX / 64), dim3(256), 0, stream>>>(xThi, xTlo, woAhi, woAlo, offs);
  defB_kernel<<<dim3(BATCH * HWPIX / 64), dim3(256), 0, stream>>>(xThi, offs, wdA, out);
}

// Round 13
// 104.865 us; speedup vs baseline: 1.0737x; 1.0737x over previous
//
#include <hip/hip_runtime.h>

// DCNv2, fp32 in/out, all matmul-shaped work on bf16 MFMA.
// Round 13: R9 base (best, 106.0us total / fused ~43us) + two levers with
// forcing mechanisms:
//  (1) depth-2 REGISTER gather pipeline, fully unrolled kk loop (static slot
//      indices) + sched_barrier(0) pinning the load issue -> compiler cannot
//      sink the prefetch (prior rounds: VGPR stayed ~52 = sunk). Loads for
//      kk+2 issue at iter kk; __syncthreads does not drain VGPR loads.
//      __launch_bounds__(256,4) caps VGPR at 128 (grid = 4 blocks/CU anyway).
//  (2) packed-f32 bilinear blend (float2 -> v_pk_fma_f32): lo/hi halves
//      share weights, ~40% fewer blend VALU.
// Everything else R9 verbatim: 2 launches, wave=cout-tile A-dedup, dbuf
// 1 barrier/kk, cvt_pk pack, swz LDS swizzle, XCD-banded bid.
// ws: xThi 8388608 | xTlo 8388608 | wdA 73728 | woAhi 36864 | woAlo 36864

#define BATCH 4
#define CIN   64
#define COUT  64
#define HH    128
#define WW    128
#define HWPIX (HH*WW)

typedef __attribute__((ext_vector_type(8))) short short8;   // 8 bf16 (4 VGPRs)
typedef __attribute__((ext_vector_type(4))) float floatx4;  // MFMA C/D
typedef __attribute__((ext_vector_type(2))) float f32x2;    // packed-f32 pair

__device__ __forceinline__ unsigned short f2bf(float f) {   // RNE f32->bf16
  unsigned int u = __float_as_uint(f);
  unsigned int r = u + 0x7fffu + ((u >> 16) & 1u);
  return (unsigned short)(r >> 16);
}
__device__ __forceinline__ float bf2f(unsigned short h) { return __uint_as_float(((unsigned int)h) << 16); }
__device__ __forceinline__ float lo16f(unsigned int u) { return __uint_as_float(u << 16); }
__device__ __forceinline__ float hi16f(unsigned int u) { return __uint_as_float(u & 0xffff0000u); }

// 2-channel bilinear blend on packed f32 pairs (lo,hi share weights ->
// v_pk_fma_f32 candidates); pack via HW RNE convert (== f2bf pair).
__device__ __forceinline__ unsigned int bilin2v(unsigned int u00, unsigned int u01,
                                                unsigned int u10, unsigned int u11,
                                                f32x2 w00, f32x2 w01, f32x2 w10, f32x2 w11) {
  f32x2 c00 = {lo16f(u00), hi16f(u00)};
  f32x2 c01 = {lo16f(u01), hi16f(u01)};
  f32x2 c10 = {lo16f(u10), hi16f(u10)};
  f32x2 c11 = {lo16f(u11), hi16f(u11)};
  f32x2 a = c00 * w00 + c01 * w01 + c10 * w10 + c11 * w11;
  unsigned int r;
  asm("v_cvt_pk_bf16_f32 %0, %1, %2" : "=v"(r) : "v"(a.x), "v"(a.y));
  return r;
}

// LDS byte-offset swizzle: fold bits 9-10 into bits 4-5 (involution, <8KB).
__device__ __forceinline__ int swz(int a) { return a ^ (((a >> 9) & 3) << 4); }

// Fused preprocessing (unchanged):
__global__ __launch_bounds__(256) void pre_kernel(const float* __restrict__ x,
                                                  const float* __restrict__ wo,
                                                  const float* __restrict__ wd,
                                                  unsigned short* __restrict__ xThi,
                                                  unsigned short* __restrict__ xTlo,
                                                  unsigned short* __restrict__ wdA,
                                                  unsigned short* __restrict__ woAhi,
                                                  unsigned short* __restrict__ woAlo) {
  int tid = threadIdx.x;
  if (blockIdx.x < 4096) {
    __shared__ float tile[32][33];   // [c_local][p_local]
    int t = blockIdx.x;
    int b = t >> 10, rem = t & 1023;
    int c0 = (rem >> 9) * 32, p0 = (rem & 511) * 32;
    int tx = tid & 31, ty = tid >> 5;      // (32,8)
    const float* xb = x + (size_t)b * CIN * HWPIX;
    size_t boff = (size_t)b * HWPIX * CIN;
#pragma unroll
    for (int i = 0; i < 4; i++)
      tile[ty + i * 8][tx] = xb[(size_t)(c0 + ty + i * 8) * HWPIX + p0 + tx];
    __syncthreads();
#pragma unroll
    for (int i = 0; i < 2; i++) {
      int tt = tid + i * 256;       // 0..511 = 32 rows * 16 cin-pairs
      int row = tt >> 4;
      int cp = tt & 15;
      float v0 = tile[cp * 2][row], v1 = tile[cp * 2 + 1][row];
      unsigned short h0 = f2bf(v0), h1 = f2bf(v1);
      unsigned short l0 = f2bf(v0 - bf2f(h0)), l1 = f2bf(v1 - bf2f(h1));
      size_t o = boff + (size_t)(p0 + row) * CIN + c0 + cp * 2;
      *(ushort2*)&xThi[o] = make_ushort2(h0, h1);
      *(ushort2*)&xTlo[o] = make_ushort2(l0, l1);
    }
  } else {
    int t = (blockIdx.x - 4096) * 256 + tid;
    if (t < 36864) {
      int j = t & 7, lane = (t >> 3) & 63, ct = (t >> 9) & 3, kc = (t >> 11) & 1, kk = t >> 12;
      int cout = ct * 16 + (lane & 15);
      int cin  = kc * 32 + (lane >> 4) * 8 + j;
      wdA[t] = f2bf(wd[(size_t)(cout * CIN + cin) * 9 + kk]);
    }
    int t2 = t - 36864;
    if (t2 >= 0 && t2 < 18432) {
      int j = t2 & 7, lane = (t2 >> 3) & 63, ct = (t2 >> 9) & 1, kc = (t2 >> 10) & 1, kk = t2 >> 11;
      int cout = ct * 16 + (lane & 15);          // conv channel 0..31 (valid < 18)
      int cin  = kc * 32 + (lane >> 4) * 8 + j;
      float v = (cout < 18) ? wo[(size_t)(cout * CIN + cin) * 9 + kk] : 0.f;
      unsigned short h = f2bf(v);
      woAhi[t2] = h;
      woAlo[t2] = f2bf(v - bf2f(h));
    }
  }
}

// Fused offset-conv + deform GEMM; R9 structure + depth-2 register pipeline.
// Block: 64 px tile (b, y, x0..x0+63), 256 thr = 4 waves.
__global__ __launch_bounds__(256, 4) void fused_dcn_kernel(const unsigned short* __restrict__ xThi,
                                                           const unsigned short* __restrict__ xTlo,
                                                           const unsigned short* __restrict__ woAhi,
                                                           const unsigned short* __restrict__ woAlo,
                                                           const unsigned short* __restrict__ wdA,
                                                           float* __restrict__ out) {
  __shared__ unsigned short sBhi2[2][4096];   // 16 KB dbuf (A: im2col hi; B: sampled)
  __shared__ unsigned short sBlo2[2][4096];   // 16 KB dbuf (A only: im2col lo)
  __shared__ float offL[18 * 64];             // 4.5 KB
  char* sHc = (char*)sBhi2;
  char* sLc = (char*)sBlo2;

  int tid = threadIdx.x;
  int hw = blockIdx.x;
  int bid = (hw & 7) * 128 + (hw >> 3);    // XCD-contiguous y bands
  int b = bid >> 8, r = bid & 255, y = r >> 1, x0 = (r & 1) << 6;

  int p1 = tid >> 2, si = tid & 3;
  int lane = tid & 63, w = tid >> 6;

  const unsigned short* xhib = xThi + (size_t)b * HWPIX * CIN;
  const unsigned short* xlob = xTlo + (size_t)b * HWPIX * CIN;

  int wq = p1 >> 4, iq = p1 & 15;
  int kcd = si >> 1, qb = si & 1;
  int wb0 = ((((wq * 2 + kcd) * 64) + qb * 32 + iq) * 8) * 2;
  int wb1 = wb0 + 256;
  int swb0 = swz(wb0), swb1 = swz(wb1);
  int brb0[4], brb1[4];
#pragma unroll
  for (int pg = 0; pg < 4; pg++) {
    brb0[pg] = swz(pg * 2048 + lane * 16);
    brb1[pg] = swz(pg * 2048 + 1024 + lane * 16);
  }

  int xp = x0 + p1;

  // ================= Phase A: offset conv (depth-2 reg pipeline) ===========
  floatx4 oacc[2];
  oacc[0] = (floatx4){0.f, 0.f, 0.f, 0.f};
  oacc[1] = (floatx4){0.f, 0.f, 0.f, 0.f};
  int ctA = w & 1, pgA = (w >> 1) * 2;

  auto ldA = [&](int kk, uint4& h0, uint4& h1, uint4& l0, uint4& l1) {
    int ys = y - 1 + kk / 3;
    int xs = xp - 1 + kk % 3;
    bool valid = (ys >= 0) && (ys < HH) && (xs >= 0) && (xs < WW);
    h0 = (uint4){0, 0, 0, 0}; h1 = h0; l0 = h0; l1 = h0;
    if (valid) {
      const unsigned short* ph = xhib + (size_t)(ys * WW + xs) * CIN + si * 16;
      const unsigned short* pl = xlob + (size_t)(ys * WW + xs) * CIN + si * 16;
      h0 = *(const uint4*)ph; h1 = *(const uint4*)(ph + 8);
      l0 = *(const uint4*)pl; l1 = *(const uint4*)(pl + 8);
    }
  };
  auto stageA = [&](int nxt, const uint4& h0, const uint4& h1, const uint4& l0, const uint4& l1) {
    *(uint4*)(sHc + nxt * 8192 + swb0) = h0;
    *(uint4*)(sHc + nxt * 8192 + swb1) = h1;
    *(uint4*)(sLc + nxt * 8192 + swb0) = l0;
    *(uint4*)(sLc + nxt * 8192 + swb1) = l1;
  };
  auto mfmaA = [&](int kk, int cur) {
    const short8* Ah = (const short8*)(woAhi + (size_t)kk * 2048);
    const short8* Al = (const short8*)(woAlo + (size_t)kk * 2048);
    short8 ah0 = Ah[ctA * 64 + lane], ah1 = Ah[128 + ctA * 64 + lane];
    short8 al0 = Al[ctA * 64 + lane], al1 = Al[128 + ctA * 64 + lane];
#pragma unroll
    for (int pgi = 0; pgi < 2; pgi++) {
      int pg = pgA + pgi;
      short8 bh0 = *(const short8*)(sHc + cur * 8192 + brb0[pg]);
      short8 bh1 = *(const short8*)(sHc + cur * 8192 + brb1[pg]);
      short8 bl0 = *(const short8*)(sLc + cur * 8192 + brb0[pg]);
      short8 bl1 = *(const short8*)(sLc + cur * 8192 + brb1[pg]);
      oacc[pgi] = __builtin_amdgcn_mfma_f32_16x16x32_bf16(ah0, bh0, oacc[pgi], 0, 0, 0);
      oacc[pgi] = __builtin_amdgcn_mfma_f32_16x16x32_bf16(ah0, bl0, oacc[pgi], 0, 0, 0);
      oacc[pgi] = __builtin_amdgcn_mfma_f32_16x16x32_bf16(al0, bh0, oacc[pgi], 0, 0, 0);
      oacc[pgi] = __builtin_amdgcn_mfma_f32_16x16x32_bf16(ah1, bh1, oacc[pgi], 0, 0, 0);
      oacc[pgi] = __builtin_amdgcn_mfma_f32_16x16x32_bf16(ah1, bl1, oacc[pgi], 0, 0, 0);
      oacc[pgi] = __builtin_amdgcn_mfma_f32_16x16x32_bf16(al1, bh1, oacc[pgi], 0, 0, 0);
    }
  };

  {
    uint4 h0s[2], h1s[2], l0s[2], l1s[2];   // static-indexed under full unroll
    ldA(0, h0s[0], h1s[0], l0s[0], l1s[0]);
    stageA(0, h0s[0], h1s[0], l0s[0], l1s[0]);
    ldA(1, h0s[1], h1s[1], l0s[1], l1s[1]);
    __syncthreads();
#pragma unroll
    for (int kk = 0; kk < 9; kk++) {
      if (kk < 7) ldA(kk + 2, h0s[kk & 1], h1s[kk & 1], l0s[kk & 1], l1s[kk & 1]);
      __builtin_amdgcn_sched_barrier(0);    // pin load issue before consume
      if (kk < 8) stageA((kk + 1) & 1, h0s[(kk + 1) & 1], h1s[(kk + 1) & 1],
                         l0s[(kk + 1) & 1], l1s[(kk + 1) & 1]);
      mfmaA(kk, kk & 1);
      __syncthreads();
    }
  }

  // offL scatter (wave w: rows ctA*16.., cols pgA*16..) then barrier.
  {
    int rowb = (lane >> 4) * 4;
    int colb = pgA * 16 + (lane & 15);
#pragma unroll
    for (int pgi = 0; pgi < 2; pgi++)
#pragma unroll
      for (int rr = 0; rr < 4; rr++) {
        int row = ctA * 16 + rowb + rr;
        if (row < 18) offL[row * 64 + colb + pgi * 16] = oacc[pgi][rr];
      }
  }
  __syncthreads();

  // ================= Phase B: sample + deform GEMM (depth-2 reg pipeline) ==
  floatx4 acc[4];
#pragma unroll
  for (int pg = 0; pg < 4; pg++) acc[pg] = (floatx4){0.f, 0.f, 0.f, 0.f};

  struct BS {
    float w00, w01, w10, w11;
    uint4 a00, a01, a10, a11, b00, b01, b10, b11;
  };
  auto ldB = [&](int kk) -> BS {
    BS s;
    float dy = offL[(2 * kk) * 64 + p1];
    float dx = offL[(2 * kk + 1) * 64 + p1];
    float ys = (float)(y - 1 + kk / 3) + dy;
    float xs = (float)(xp - 1 + kk % 3) + dx;
    float y0f = floorf(ys), x0f = floorf(xs);
    float wy = ys - y0f, wx = xs - x0f;
    int iy0 = (int)y0f, ix0 = (int)x0f;
    int iy1 = iy0 + 1, ix1 = ix0 + 1;
    s.w00 = (1.f - wy) * (1.f - wx); s.w01 = (1.f - wy) * wx;
    s.w10 = wy * (1.f - wx);         s.w11 = wy * wx;
    bool vy0 = (iy0 >= 0) && (iy0 < HH), vy1 = (iy1 >= 0) && (iy1 < HH);
    bool vx0 = (ix0 >= 0) && (ix0 < WW), vx1 = (ix1 >= 0) && (ix1 < WW);
    if (!(vy0 && vx0)) s.w00 = 0.f;
    if (!(vy0 && vx1)) s.w01 = 0.f;
    if (!(vy1 && vx0)) s.w10 = 0.f;
    if (!(vy1 && vx1)) s.w11 = 0.f;
    int cy0 = min(max(iy0, 0), HH - 1), cy1 = min(max(iy1, 0), HH - 1);
    int cx0 = min(max(ix0, 0), WW - 1), cx1 = min(max(ix1, 0), WW - 1);
    const unsigned short* q00 = xhib + (size_t)(cy0 * WW + cx0) * CIN + si * 16;
    const unsigned short* q01 = xhib + (size_t)(cy0 * WW + cx1) * CIN + si * 16;
    const unsigned short* q10 = xhib + (size_t)(cy1 * WW + cx0) * CIN + si * 16;
    const unsigned short* q11 = xhib + (size_t)(cy1 * WW + cx1) * CIN + si * 16;
    s.a00 = *(const uint4*)q00; s.a01 = *(const uint4*)q01;
    s.a10 = *(const uint4*)q10; s.a11 = *(const uint4*)q11;
    s.b00 = *(const uint4*)(q00 + 8); s.b01 = *(const uint4*)(q01 + 8);
    s.b10 = *(const uint4*)(q10 + 8); s.b11 = *(const uint4*)(q11 + 8);
    return s;
  };
  auto blendStoreB = [&](int nxt, const BS& s) {
    f32x2 w00 = {s.w00, s.w00}, w01 = {s.w01, s.w01};
    f32x2 w10 = {s.w10, s.w10}, w11 = {s.w11, s.w11};
    uint4 o0, o1;
    o0.x = bilin2v(s.a00.x, s.a01.x, s.a10.x, s.a11.x, w00, w01, w10, w11);
    o0.y = bilin2v(s.a00.y, s.a01.y, s.a10.y, s.a11.y, w00, w01, w10, w11);
    o0.z = bilin2v(s.a00.z, s.a01.z, s.a10.z, s.a11.z, w00, w01, w10, w11);
    o0.w = bilin2v(s.a00.w, s.a01.w, s.a10.w, s.a11.w, w00, w01, w10, w11);
    o1.x = bilin2v(s.b00.x, s.b01.x, s.b10.x, s.b11.x, w00, w01, w10, w11);
    o1.y = bilin2v(s.b00.y, s.b01.y, s.b10.y, s.b11.y, w00, w01, w10, w11);
    o1.z = bilin2v(s.b00.z, s.b01.z, s.b10.z, s.b11.z, w00, w01, w10, w11);
    o1.w = bilin2v(s.b00.w, s.b01.w, s.b10.w, s.b11.w, w00, w01, w10, w11);
    *(uint4*)(sHc + nxt * 8192 + swb0) = o0;
    *(uint4*)(sHc + nxt * 8192 + swb1) = o1;
  };
  auto mfmaB = [&](int kk, int cur) {
    const short8* Ap = (const short8*)(wdA + (size_t)kk * 4096);
    short8 a0 = Ap[w * 64 + lane];          // this wave's ct only (A dedup)
    short8 a1 = Ap[256 + w * 64 + lane];
#pragma unroll
    for (int pg = 0; pg < 4; pg++) {
      short8 bv0 = *(const short8*)(sHc + cur * 8192 + brb0[pg]);
      short8 bv1 = *(const short8*)(sHc + cur * 8192 + brb1[pg]);
      acc[pg] = __builtin_amdgcn_mfma_f32_16x16x32_bf16(a0, bv0, acc[pg], 0, 0, 0);
      acc[pg] = __builtin_amdgcn_mfma_f32_16x16x32_bf16(a1, bv1, acc[pg], 0, 0, 0);
    }
  };

  {
    BS sb[2];                                // static-indexed under full unroll
    sb[0] = ldB(0);
    blendStoreB(0, sb[0]);
    sb[1] = ldB(1);
    __syncthreads();
#pragma unroll
    for (int kk = 0; kk < 9; kk++) {
      if (kk < 7) sb[kk & 1] = ldB(kk + 2);  // issue gathers 2 ahead
      __builtin_amdgcn_sched_barrier(0);     // pin load issue before consume
      if (kk < 8) blendStoreB((kk + 1) & 1, sb[(kk + 1) & 1]);
      mfmaB(kk, kk & 1);
      __syncthreads();
    }
  }

  // D: col = lane&15 (px within pg tile), row = (lane>>4)*4 + reg;
  // wave w owns couts [16w, 16w+16) for all 4 px-groups.
  int rowb = (lane >> 4) * 4;
  float* outb = out + (size_t)b * COUT * HWPIX + y * WW + x0 + (lane & 15);
#pragma unroll
  for (int pg = 0; pg < 4; pg++)
#pragma unroll
    for (int rr = 0; rr < 4; rr++)
      outb[(size_t)(w * 16 + rowb + rr) * HWPIX + pg * 16] = acc[pg][rr];
}

extern "C" void kernel_launch(void* const* d_in, const int* in_sizes, int n_in,
                              void* d_out, int out_size, void* d_ws, size_t ws_size,
                              hipStream_t stream) {
  const float* x  = (const float*)d_in[0];
  const float* wo = (const float*)d_in[1];
  const float* wd = (const float*)d_in[2];
  float* out = (float*)d_out;

  char* wsb = (char*)d_ws;
  unsigned short* xThi  = (unsigned short*)wsb;                         // 8,388,608 B
  unsigned short* xTlo  = (unsigned short*)(wsb + 8388608);             // 8,388,608 B
  unsigned short* wdA   = (unsigned short*)(wsb + 16777216);            // 73,728 B
  unsigned short* woAhi = (unsigned short*)(wsb + 16777216 + 73728);    // 36,864 B
  unsigned short* woAlo = (unsigned short*)(wsb + 16850944 + 36864);    // 36,864 B

  pre_kernel<<<dim3(4096 + 216), dim3(256), 0, stream>>>(x, wo, wd, xThi, xTlo, wdA, woAhi, woAlo);
  fused_dcn_kernel<<<dim3(BATCH * HWPIX / 64), dim3(256), 0, stream>>>(xThi, xTlo, woAhi, woAlo, wdA, out);
}